// Round 1
// baseline (639.744 us; speedup 1.0000x reference)
//
#include <hip/hip_runtime.h>
#include <math.h>

#define L_ 4096
#define B_ 4
#define D_ 512
#define V_ 1000
#define VP 1024
#define BD 2048  // B_*D_

// ---------------------------------------------------------------------------
// kG: G[b] = xb_b^T xb_b   (D x D, K = L)  64x64 tiles, 4x4 per thread
// x layout: (L, B, D) -> x[l*BD + b*D + d]
// ---------------------------------------------------------------------------
__global__ __launch_bounds__(256) void kG(const float* __restrict__ x,
                                          float* __restrict__ G) {
  const int b = blockIdx.z;
  const int i0 = blockIdx.x * 64, j0 = blockIdx.y * 64;
  __shared__ float As[16][64];
  __shared__ float Bs[16][64];
  float acc[4][4] = {};
  const int tid = threadIdx.x;
  const int tx = tid & 15, ty = tid >> 4;
  const int lr = tid >> 4, lc = (tid & 15) * 4;

  for (int l0 = 0; l0 < L_; l0 += 16) {
    const float* xr = x + (size_t)(l0 + lr) * BD + b * D_;
    float4 a4 = *(const float4*)(xr + i0 + lc);
    float4 b4 = *(const float4*)(xr + j0 + lc);
    As[lr][lc + 0] = a4.x; As[lr][lc + 1] = a4.y;
    As[lr][lc + 2] = a4.z; As[lr][lc + 3] = a4.w;
    Bs[lr][lc + 0] = b4.x; Bs[lr][lc + 1] = b4.y;
    Bs[lr][lc + 2] = b4.z; Bs[lr][lc + 3] = b4.w;
    __syncthreads();
#pragma unroll
    for (int k = 0; k < 16; ++k) {
      float av[4], bv[4];
#pragma unroll
      for (int r = 0; r < 4; ++r) av[r] = As[k][ty * 4 + r];
#pragma unroll
      for (int cc = 0; cc < 4; ++cc) bv[cc] = Bs[k][tx * 4 + cc];
#pragma unroll
      for (int r = 0; r < 4; ++r)
#pragma unroll
        for (int cc = 0; cc < 4; ++cc)
          acc[r][cc] = fmaf(av[r], bv[cc], acc[r][cc]);
    }
    __syncthreads();
  }
  float* Gb = G + (size_t)b * D_ * D_;
#pragma unroll
  for (int r = 0; r < 4; ++r) {
    float4 res = make_float4(acc[r][0], acc[r][1], acc[r][2], acc[r][3]);
    *(float4*)(Gb + (size_t)(i0 + ty * 4 + r) * D_ + j0 + tx * 4) = res;
  }
}

// ---------------------------------------------------------------------------
// kS: s[b][d] = sum_l x[l,b,d]   (atomic partials; s pre-zeroed by memset)
// ---------------------------------------------------------------------------
__global__ __launch_bounds__(256) void kS(const float* __restrict__ x,
                                          float* __restrict__ s) {
  const int b = blockIdx.y;
  const int l0 = blockIdx.x * 64;
  const int tid = threadIdx.x;
  float a0 = 0.f, a1 = 0.f;
  for (int l = 0; l < 64; ++l) {
    const float* xr = x + (size_t)(l0 + l) * BD + b * D_;
    a0 += xr[tid];
    a1 += xr[tid + 256];
  }
  atomicAdd(&s[b * D_ + tid], a0);
  atomicAdd(&s[b * D_ + tid + 256], a1);
}

// ---------------------------------------------------------------------------
// kC: c[b][l] = dot(x[l,b,:], Wb)   one wave per row
// ---------------------------------------------------------------------------
__global__ __launch_bounds__(256) void kC(const float* __restrict__ x,
                                          const float* __restrict__ Wb,
                                          float* __restrict__ c) {
  const int b = blockIdx.y;
  const int w = threadIdx.x >> 6, lane = threadIdx.x & 63;
  const int l = blockIdx.x * 4 + w;
  const float* xr = x + (size_t)l * BD + b * D_;
  float sum = 0.f;
#pragma unroll
  for (int i = 0; i < 8; ++i) sum += xr[lane + i * 64] * Wb[lane + i * 64];
  for (int off = 32; off; off >>= 1) sum += __shfl_down(sum, off);
  if (lane == 0) c[b * L_ + l] = sum;
}

// ---------------------------------------------------------------------------
// kT: t[b][v] = dot(Lw[v,:], s[b,:])  one wave per (b,v); pad v>=V_ with 0
// ---------------------------------------------------------------------------
__global__ __launch_bounds__(256) void kT(const float* __restrict__ Lw,
                                          const float* __restrict__ s,
                                          float* __restrict__ t) {
  const int w = threadIdx.x >> 6, lane = threadIdx.x & 63;
  const int wid = blockIdx.x * 4 + w;  // 0..4095
  const int b = wid >> 10, v = wid & 1023;
  float sum = 0.f;
  if (v < V_) {
    const float* lr = Lw + (size_t)v * D_;
    const float* sb = s + b * D_;
#pragma unroll
    for (int i = 0; i < 8; ++i) sum += lr[lane + i * 64] * sb[lane + i * 64];
  }
  for (int off = 32; off; off >>= 1) sum += __shfl_down(sum, off);
  if (lane == 0) t[b * VP + v] = (v < V_) ? sum : 0.f;
}

// ---------------------------------------------------------------------------
// kM: M[b] = Ww @ G[b]   (D x D, K = D)
// ---------------------------------------------------------------------------
__global__ __launch_bounds__(256) void kM(const float* __restrict__ Ww,
                                          const float* __restrict__ G,
                                          float* __restrict__ M) {
  const int b = blockIdx.z;
  const int i0 = blockIdx.x * 64, j0 = blockIdx.y * 64;
  __shared__ float As[16][64];
  __shared__ float Bs[16][64];
  float acc[4][4] = {};
  const int tid = threadIdx.x;
  const int tx = tid & 15, ty = tid >> 4;
  const int ar = tid & 63, ak = (tid >> 6) * 4;   // transposed A load
  const int bk = tid >> 4, bj = (tid & 15) * 4;   // direct B load
  const float* Gb = G + (size_t)b * D_ * D_;

  for (int k0 = 0; k0 < D_; k0 += 16) {
    float4 a4 = *(const float4*)(Ww + (size_t)(i0 + ar) * D_ + k0 + ak);
    As[ak + 0][ar] = a4.x; As[ak + 1][ar] = a4.y;
    As[ak + 2][ar] = a4.z; As[ak + 3][ar] = a4.w;
    float4 b4 = *(const float4*)(Gb + (size_t)(k0 + bk) * D_ + j0 + bj);
    Bs[bk][bj + 0] = b4.x; Bs[bk][bj + 1] = b4.y;
    Bs[bk][bj + 2] = b4.z; Bs[bk][bj + 3] = b4.w;
    __syncthreads();
#pragma unroll
    for (int k = 0; k < 16; ++k) {
      float av[4], bv[4];
#pragma unroll
      for (int r = 0; r < 4; ++r) av[r] = As[k][ty * 4 + r];
#pragma unroll
      for (int cc = 0; cc < 4; ++cc) bv[cc] = Bs[k][tx * 4 + cc];
#pragma unroll
      for (int r = 0; r < 4; ++r)
#pragma unroll
        for (int cc = 0; cc < 4; ++cc)
          acc[r][cc] = fmaf(av[r], bv[cc], acc[r][cc]);
    }
    __syncthreads();
  }
  float* Mb = M + (size_t)b * D_ * D_;
#pragma unroll
  for (int r = 0; r < 4; ++r) {
    float4 res = make_float4(acc[r][0], acc[r][1], acc[r][2], acc[r][3]);
    *(float4*)(Mb + (size_t)(i0 + ty * 4 + r) * D_ + j0 + tx * 4) = res;
  }
}

// ---------------------------------------------------------------------------
// kP: P[b] = M[b] @ Lw^T   (D x VP, K = D); cols >= V_ are zero
// ---------------------------------------------------------------------------
__global__ __launch_bounds__(256) void kP(const float* __restrict__ M,
                                          const float* __restrict__ Lw,
                                          float* __restrict__ P) {
  const int b = blockIdx.z;
  const int d0 = blockIdx.x * 64, v0 = blockIdx.y * 64;
  __shared__ float As[16][64];
  __shared__ float Bs[16][64];
  float acc[4][4] = {};
  const int tid = threadIdx.x;
  const int tx = tid & 15, ty = tid >> 4;
  const int ar = tid & 63, ak = (tid >> 6) * 4;  // both operands transposed-load
  const float* Mb = M + (size_t)b * D_ * D_;

  for (int k0 = 0; k0 < D_; k0 += 16) {
    float4 a4 = *(const float4*)(Mb + (size_t)(d0 + ar) * D_ + k0 + ak);
    As[ak + 0][ar] = a4.x; As[ak + 1][ar] = a4.y;
    As[ak + 2][ar] = a4.z; As[ak + 3][ar] = a4.w;
    const int v = v0 + ar;
    float4 b4 = make_float4(0.f, 0.f, 0.f, 0.f);
    if (v < V_) b4 = *(const float4*)(Lw + (size_t)v * D_ + k0 + ak);
    Bs[ak + 0][ar] = b4.x; Bs[ak + 1][ar] = b4.y;
    Bs[ak + 2][ar] = b4.z; Bs[ak + 3][ar] = b4.w;
    __syncthreads();
#pragma unroll
    for (int k = 0; k < 16; ++k) {
      float av[4], bv[4];
#pragma unroll
      for (int r = 0; r < 4; ++r) av[r] = As[k][ty * 4 + r];
#pragma unroll
      for (int cc = 0; cc < 4; ++cc) bv[cc] = Bs[k][tx * 4 + cc];
#pragma unroll
      for (int r = 0; r < 4; ++r)
#pragma unroll
        for (int cc = 0; cc < 4; ++cc)
          acc[r][cc] = fmaf(av[r], bv[cc], acc[r][cc]);
    }
    __syncthreads();
  }
  float* Pb = P + (size_t)b * D_ * VP;
#pragma unroll
  for (int r = 0; r < 4; ++r) {
    float4 res = make_float4(acc[r][0], acc[r][1], acc[r][2], acc[r][3]);
    *(float4*)(Pb + (size_t)(d0 + ty * 4 + r) * VP + v0 + tx * 4) = res;
  }
}

// ---------------------------------------------------------------------------
// kLogits: logits[b,l,v] = sum_k x[l,b,k] P[b][k,v] + c[b,l]*t[b,v] + Lb[v]
// stored (B, L, VP)
// ---------------------------------------------------------------------------
__global__ __launch_bounds__(256) void kLogits(const float* __restrict__ x,
                                               const float* __restrict__ P,
                                               const float* __restrict__ c,
                                               const float* __restrict__ t,
                                               const float* __restrict__ Lb,
                                               float* __restrict__ logits) {
  const int b = blockIdx.z;
  const int l0 = blockIdx.x * 64, v0 = blockIdx.y * 64;
  __shared__ float As[16][64];
  __shared__ float Bs[16][64];
  float acc[4][4] = {};
  const int tid = threadIdx.x;
  const int tx = tid & 15, ty = tid >> 4;
  const int ar = tid & 63, ak = (tid >> 6) * 4;  // transposed A load (x rows)
  const int bk = tid >> 4, bj = (tid & 15) * 4;  // direct B load (P rows)
  const float* Pb = P + (size_t)b * D_ * VP;

  for (int k0 = 0; k0 < D_; k0 += 16) {
    float4 a4 = *(const float4*)(x + (size_t)(l0 + ar) * BD + b * D_ + k0 + ak);
    As[ak + 0][ar] = a4.x; As[ak + 1][ar] = a4.y;
    As[ak + 2][ar] = a4.z; As[ak + 3][ar] = a4.w;
    float4 b4 = *(const float4*)(Pb + (size_t)(k0 + bk) * VP + v0 + bj);
    Bs[bk][bj + 0] = b4.x; Bs[bk][bj + 1] = b4.y;
    Bs[bk][bj + 2] = b4.z; Bs[bk][bj + 3] = b4.w;
    __syncthreads();
#pragma unroll
    for (int k = 0; k < 16; ++k) {
      float av[4], bv[4];
#pragma unroll
      for (int r = 0; r < 4; ++r) av[r] = As[k][ty * 4 + r];
#pragma unroll
      for (int cc = 0; cc < 4; ++cc) bv[cc] = Bs[k][tx * 4 + cc];
#pragma unroll
      for (int r = 0; r < 4; ++r)
#pragma unroll
        for (int cc = 0; cc < 4; ++cc)
          acc[r][cc] = fmaf(av[r], bv[cc], acc[r][cc]);
    }
    __syncthreads();
  }
#pragma unroll
  for (int r = 0; r < 4; ++r) {
    const int l = l0 + ty * 4 + r;
    const float cl = c[b * L_ + l];
    float4 res;
    float* rp = &res.x;
#pragma unroll
    for (int cc = 0; cc < 4; ++cc) {
      const int v = v0 + tx * 4 + cc;
      float val = acc[r][cc] + cl * t[b * VP + v];
      if (v < V_) val += Lb[v];
      rp[cc] = val;
    }
    *(float4*)(logits + ((size_t)b * L_ + l) * VP + v0 + tx * 4) = res;
  }
}

// ---------------------------------------------------------------------------
// kLsm: log_softmax over V per (b,l) row; write out (L, B, V)
// ---------------------------------------------------------------------------
__global__ __launch_bounds__(256) void kLsm(const float* __restrict__ logits,
                                            float* __restrict__ out) {
  const int l = blockIdx.x, b = blockIdx.y;
  const int tid = threadIdx.x;
  const int lane = tid & 63, w = tid >> 6;
  const float* row = logits + ((size_t)b * L_ + l) * VP;
  float vals[4];
  float vmax = -__builtin_inff();
#pragma unroll
  for (int j = 0; j < 4; ++j) {
    const int v = tid + j * 256;
    vals[j] = (v < V_) ? row[v] : -__builtin_inff();
    vmax = fmaxf(vmax, vals[j]);
  }
  for (int off = 32; off; off >>= 1) vmax = fmaxf(vmax, __shfl_down(vmax, off));
  __shared__ float red_max[4];
  __shared__ float red_sum[4];
  if (lane == 0) red_max[w] = vmax;
  __syncthreads();
  const float m = fmaxf(fmaxf(red_max[0], red_max[1]),
                        fmaxf(red_max[2], red_max[3]));
  float se = 0.f;
#pragma unroll
  for (int j = 0; j < 4; ++j) se += expf(vals[j] - m);  // -inf -> 0
  for (int off = 32; off; off >>= 1) se += __shfl_down(se, off);
  if (lane == 0) red_sum[w] = se;
  __syncthreads();
  const float lse = m + logf(red_sum[0] + red_sum[1] + red_sum[2] + red_sum[3]);
  float* orow = out + (size_t)l * (B_ * V_) + b * V_;
#pragma unroll
  for (int j = 0; j < 4; ++j) {
    const int v = tid + j * 256;
    if (v < V_) orow[v] = vals[j] - lse;
  }
}

// ---------------------------------------------------------------------------
extern "C" void kernel_launch(void* const* d_in, const int* in_sizes, int n_in,
                              void* d_out, int out_size, void* d_ws,
                              size_t ws_size, hipStream_t stream) {
  const float* x  = (const float*)d_in[0];
  const float* Ww = (const float*)d_in[1];
  const float* Wb = (const float*)d_in[2];
  const float* Lw = (const float*)d_in[3];
  const float* Lb = (const float*)d_in[4];
  float* ws = (float*)d_ws;

  const size_t nG = (size_t)B_ * D_ * D_;      // 1,048,576
  const size_t nP = (size_t)B_ * D_ * VP;      // 2,097,152
  float* G      = ws;
  float* M      = G + nG;
  float* P      = M + nG;
  float* s      = P + nP;                      // B*D
  float* c      = s + (size_t)B_ * D_;         // B*L
  float* t      = c + (size_t)B_ * L_;         // B*VP
  float* logits = t + (size_t)B_ * VP;         // B*L*VP

  hipMemsetAsync(s, 0, (size_t)B_ * D_ * sizeof(float), stream);

  kG<<<dim3(8, 8, B_), 256, 0, stream>>>(x, G);
  kS<<<dim3(64, B_), 256, 0, stream>>>(x, s);
  kC<<<dim3(L_ / 4, B_), 256, 0, stream>>>(x, Wb, c);
  kM<<<dim3(8, 8, B_), 256, 0, stream>>>(Ww, G, M);
  kT<<<dim3(1024), 256, 0, stream>>>(Lw, s, t);
  kP<<<dim3(8, 16, B_), 256, 0, stream>>>(M, Lw, P);
  kLogits<<<dim3(64, 16, B_), 256, 0, stream>>>(x, P, c, t, Lb, logits);
  kLsm<<<dim3(L_, B_), 256, 0, stream>>>(logits, (float*)d_out);
}

// Round 2
// 270.876 us; speedup vs baseline: 2.3618x; 2.3618x over previous
//
#include <hip/hip_runtime.h>
#include <math.h>

#define L_ 4096
#define B_ 4
#define D_ 512
#define V_ 1000
#define VP 1024
#define BD 2048  // B_*D_
#define NCH 8    // split-K chunks for kGbf

typedef __attribute__((ext_vector_type(8))) short short8;
typedef __attribute__((ext_vector_type(4))) float f32x4;
typedef __attribute__((ext_vector_type(4))) short short4v;

__device__ __forceinline__ short f2bf(float f) {
  unsigned u = __float_as_uint(f);
  unsigned r = (u + 0x7FFFu + ((u >> 16) & 1u)) >> 16;
  return (short)r;
}

// ---------------------------------------------------------------------------
// kCastX: x (L,B,D) fp32 -> xbf (B,L,D) bf16  and  xT (B,D,L) bf16
// ---------------------------------------------------------------------------
__global__ __launch_bounds__(256) void kCastX(const float* __restrict__ x,
                                              short* __restrict__ xbf,
                                              short* __restrict__ xT) {
  const int l0 = blockIdx.x * 64, d0 = blockIdx.y * 64, b = blockIdx.z;
  __shared__ short tile[64 * 72];  // tile[d_local][l_local], stride 72
  const int tid = threadIdx.x;
  const int r = tid >> 2;          // 0..63 (l_local in phase 1, d_local in ph 2)
  const int c0 = (tid & 3) * 16;   // 0,16,32,48

  short sv[16];
  const float* src = x + (size_t)(l0 + r) * BD + b * D_ + d0 + c0;
#pragma unroll
  for (int q = 0; q < 4; ++q) {
    float4 f = *(const float4*)(src + q * 4);
    sv[q * 4 + 0] = f2bf(f.x); sv[q * 4 + 1] = f2bf(f.y);
    sv[q * 4 + 2] = f2bf(f.z); sv[q * 4 + 3] = f2bf(f.w);
  }
  // row-major store to xbf
  short* dst = xbf + ((size_t)b * L_ + l0 + r) * D_ + d0 + c0;
  *(short8*)(dst)     = *(short8*)(sv);
  *(short8*)(dst + 8) = *(short8*)(sv + 8);
  // scatter into transpose tile
#pragma unroll
  for (int i = 0; i < 16; ++i) tile[(c0 + i) * 72 + r] = sv[i];
  __syncthreads();
  // write xT rows (d-major, l contiguous)
  short* tdst = xT + ((size_t)b * D_ + d0 + r) * L_ + l0 + c0;
  *(short8*)(tdst)     = *(const short8*)(tile + r * 72 + c0);
  *(short8*)(tdst + 8) = *(const short8*)(tile + r * 72 + c0 + 8);
}

// ---------------------------------------------------------------------------
// kS: s[b][d] = sum_l x[l,b,d]
// ---------------------------------------------------------------------------
__global__ __launch_bounds__(256) void kS(const float* __restrict__ x,
                                          float* __restrict__ s) {
  const int b = blockIdx.y;
  const int l0 = blockIdx.x * 64;
  const int tid = threadIdx.x;
  float a0 = 0.f, a1 = 0.f;
  for (int l = 0; l < 64; ++l) {
    const float* xr = x + (size_t)(l0 + l) * BD + b * D_;
    a0 += xr[tid];
    a1 += xr[tid + 256];
  }
  atomicAdd(&s[b * D_ + tid], a0);
  atomicAdd(&s[b * D_ + tid + 256], a1);
}

// ---------------------------------------------------------------------------
// kC: c[b][l] = dot(x[l,b,:], Wb)
// ---------------------------------------------------------------------------
__global__ __launch_bounds__(256) void kC(const float* __restrict__ x,
                                          const float* __restrict__ Wb,
                                          float* __restrict__ c) {
  const int b = blockIdx.y;
  const int w = threadIdx.x >> 6, lane = threadIdx.x & 63;
  const int l = blockIdx.x * 4 + w;
  const float* xr = x + (size_t)l * BD + b * D_;
  float sum = 0.f;
#pragma unroll
  for (int i = 0; i < 8; ++i) sum += xr[lane + i * 64] * Wb[lane + i * 64];
  for (int off = 32; off; off >>= 1) sum += __shfl_down(sum, off);
  if (lane == 0) c[b * L_ + l] = sum;
}

// ---------------------------------------------------------------------------
// kT: t[b][v] = dot(Lw[v,:], s[b,:]); v >= V_ -> 0
// ---------------------------------------------------------------------------
__global__ __launch_bounds__(256) void kT(const float* __restrict__ Lw,
                                          const float* __restrict__ s,
                                          float* __restrict__ t) {
  const int w = threadIdx.x >> 6, lane = threadIdx.x & 63;
  const int wid = blockIdx.x * 4 + w;
  const int b = wid >> 10, v = wid & 1023;
  float sum = 0.f;
  if (v < V_) {
    const float* lr = Lw + (size_t)v * D_;
    const float* sb = s + b * D_;
#pragma unroll
    for (int i = 0; i < 8; ++i) sum += lr[lane + i * 64] * sb[lane + i * 64];
  }
  for (int off = 32; off; off >>= 1) sum += __shfl_down(sum, off);
  if (lane == 0) t[b * VP + v] = (v < V_) ? sum : 0.f;
}

// ---------------------------------------------------------------------------
// kGbf: Gpart[z] = xT_b[:, chunk]^ . xT_b[:, chunk]^T  (128x128 MFMA tiles)
// z = b*NCH + ch ; K-range = [ch*512, ch*512+512)
// ---------------------------------------------------------------------------
__global__ __launch_bounds__(256) void kGbf(const short* __restrict__ xT,
                                            float* __restrict__ Gpart) {
  const int z = blockIdx.z;
  const int b = z >> 3, ch = z & 7;
  const int i0 = blockIdx.x * 128, j0 = blockIdx.y * 128;
  const short* Ab = xT + (size_t)b * D_ * L_;
  __shared__ short As[128 * 64];
  __shared__ short Bs[128 * 64];
  f32x4 acc[4][4] = {};
  const int tid = threadIdx.x;
  const int w = tid >> 6, lane = tid & 63;
  const int quad = lane >> 4, mcol = lane & 15;
  const int wr0 = (w & 1) * 64, wc0 = (w >> 1) * 64;
  const int kbase = ch * 512;

  for (int k0 = kbase; k0 < kbase + 512; k0 += 64) {
#pragma unroll
    for (int q = 0; q < 4; ++q) {
      const int u = q * 256 + tid;
      const int row = u >> 3, blk = u & 7;
      const int phys = blk ^ (row & 7);
      *(short8*)(As + row * 64 + phys * 8) =
          *(const short8*)(Ab + (size_t)(i0 + row) * L_ + k0 + blk * 8);
      *(short8*)(Bs + row * 64 + phys * 8) =
          *(const short8*)(Ab + (size_t)(j0 + row) * L_ + k0 + blk * 8);
    }
    __syncthreads();
#pragma unroll
    for (int s = 0; s < 2; ++s) {
      short8 af[4], bf[4];
#pragma unroll
      for (int i = 0; i < 4; ++i) {
        const int arow = wr0 + i * 16 + mcol;
        const int ablk = (s * 4 + quad) ^ (arow & 7);
        af[i] = *(const short8*)(As + arow * 64 + ablk * 8);
        const int brow = wc0 + i * 16 + mcol;
        const int bblk = (s * 4 + quad) ^ (brow & 7);
        bf[i] = *(const short8*)(Bs + brow * 64 + bblk * 8);
      }
#pragma unroll
      for (int i = 0; i < 4; ++i)
#pragma unroll
        for (int j = 0; j < 4; ++j)
          acc[i][j] = __builtin_amdgcn_mfma_f32_16x16x32_bf16(af[i], bf[j],
                                                              acc[i][j], 0, 0, 0);
    }
    __syncthreads();
  }
  float* Gp = Gpart + (size_t)z * (D_ * D_);
#pragma unroll
  for (int i = 0; i < 4; ++i)
#pragma unroll
    for (int j = 0; j < 4; ++j) {
      const int col = j0 + wc0 + j * 16 + mcol;
#pragma unroll
      for (int r = 0; r < 4; ++r) {
        const int rowi = i0 + wr0 + i * 16 + quad * 4 + r;
        Gp[(size_t)rowi * D_ + col] = acc[i][j][r];
      }
    }
}

// ---------------------------------------------------------------------------
// kGreduce: G = sum_ch Gpart
// ---------------------------------------------------------------------------
__global__ __launch_bounds__(256) void kGreduce(const float* __restrict__ Gpart,
                                                float* __restrict__ G) {
  const int idx = blockIdx.x * 256 + threadIdx.x;  // float4 index
  const int b = idx >> 16, e = idx & 65535;
  f32x4 sum = {};
#pragma unroll
  for (int ch = 0; ch < NCH; ++ch)
    sum += *(const f32x4*)(Gpart + ((size_t)(b * NCH + ch) * (D_ * D_)) + e * 4);
  *(f32x4*)(G + (size_t)b * (D_ * D_) + e * 4) = sum;
}

// ---------------------------------------------------------------------------
// kM: M[b] = Ww @ G[b]   (fp32, 64x64 tiles)
// ---------------------------------------------------------------------------
__global__ __launch_bounds__(256) void kM(const float* __restrict__ Ww,
                                          const float* __restrict__ G,
                                          float* __restrict__ M) {
  const int b = blockIdx.z;
  const int i0 = blockIdx.x * 64, j0 = blockIdx.y * 64;
  __shared__ float As[16][64];
  __shared__ float Bs[16][64];
  float acc[4][4] = {};
  const int tid = threadIdx.x;
  const int tx = tid & 15, ty = tid >> 4;
  const int ar = tid & 63, ak = (tid >> 6) * 4;
  const int bk = tid >> 4, bj = (tid & 15) * 4;
  const float* Gb = G + (size_t)b * D_ * D_;

  for (int k0 = 0; k0 < D_; k0 += 16) {
    float4 a4 = *(const float4*)(Ww + (size_t)(i0 + ar) * D_ + k0 + ak);
    As[ak + 0][ar] = a4.x; As[ak + 1][ar] = a4.y;
    As[ak + 2][ar] = a4.z; As[ak + 3][ar] = a4.w;
    float4 b4 = *(const float4*)(Gb + (size_t)(k0 + bk) * D_ + j0 + bj);
    Bs[bk][bj + 0] = b4.x; Bs[bk][bj + 1] = b4.y;
    Bs[bk][bj + 2] = b4.z; Bs[bk][bj + 3] = b4.w;
    __syncthreads();
#pragma unroll
    for (int k = 0; k < 16; ++k) {
      float av[4], bv[4];
#pragma unroll
      for (int r = 0; r < 4; ++r) av[r] = As[k][ty * 4 + r];
#pragma unroll
      for (int cc = 0; cc < 4; ++cc) bv[cc] = Bs[k][tx * 4 + cc];
#pragma unroll
      for (int r = 0; r < 4; ++r)
#pragma unroll
        for (int cc = 0; cc < 4; ++cc)
          acc[r][cc] = fmaf(av[r], bv[cc], acc[r][cc]);
    }
    __syncthreads();
  }
  float* Mb = M + (size_t)b * D_ * D_;
#pragma unroll
  for (int r = 0; r < 4; ++r) {
    float4 res = make_float4(acc[r][0], acc[r][1], acc[r][2], acc[r][3]);
    *(float4*)(Mb + (size_t)(i0 + ty * 4 + r) * D_ + j0 + tx * 4) = res;
  }
}

// ---------------------------------------------------------------------------
// kP: Ptb[b][v][d] = sum_j Lw[v,j] * M[b][d,j]   (fp32 compute, bf16 out)
// rows v >= V_ are zero (Lw tile zero-filled)
// ---------------------------------------------------------------------------
__global__ __launch_bounds__(256) void kP(const float* __restrict__ M,
                                          const float* __restrict__ Lw,
                                          short* __restrict__ Ptb) {
  const int b = blockIdx.z;
  const int v0 = blockIdx.x * 64, d0 = blockIdx.y * 64;
  __shared__ float As[16][64];  // As[k][v]
  __shared__ float Bs[16][64];  // Bs[k][d]
  float acc[4][4] = {};
  const int tid = threadIdx.x;
  const int tx = tid & 15, ty = tid >> 4;
  const int ar = tid & 63, ak = (tid >> 6) * 4;
  const float* Mb = M + (size_t)b * D_ * D_;

  for (int k0 = 0; k0 < D_; k0 += 16) {
    const int v = v0 + ar;
    float4 a4 = make_float4(0.f, 0.f, 0.f, 0.f);
    if (v < V_) a4 = *(const float4*)(Lw + (size_t)v * D_ + k0 + ak);
    As[ak + 0][ar] = a4.x; As[ak + 1][ar] = a4.y;
    As[ak + 2][ar] = a4.z; As[ak + 3][ar] = a4.w;
    float4 b4 = *(const float4*)(Mb + (size_t)(d0 + ar) * D_ + k0 + ak);
    Bs[ak + 0][ar] = b4.x; Bs[ak + 1][ar] = b4.y;
    Bs[ak + 2][ar] = b4.z; Bs[ak + 3][ar] = b4.w;
    __syncthreads();
#pragma unroll
    for (int k = 0; k < 16; ++k) {
      float av[4], bv[4];
#pragma unroll
      for (int r = 0; r < 4; ++r) av[r] = As[k][ty * 4 + r];
#pragma unroll
      for (int cc = 0; cc < 4; ++cc) bv[cc] = Bs[k][tx * 4 + cc];
#pragma unroll
      for (int r = 0; r < 4; ++r)
#pragma unroll
        for (int cc = 0; cc < 4; ++cc)
          acc[r][cc] = fmaf(av[r], bv[cc], acc[r][cc]);
    }
    __syncthreads();
  }
  short* Pb = Ptb + (size_t)b * VP * D_;
#pragma unroll
  for (int r = 0; r < 4; ++r) {
    short4v res;
#pragma unroll
    for (int cc = 0; cc < 4; ++cc) res[cc] = f2bf(acc[r][cc]);
    *(short4v*)(Pb + (size_t)(v0 + ty * 4 + r) * D_ + d0 + tx * 4) = res;
  }
}

// ---------------------------------------------------------------------------
// kLogitsBf: logits[b,l,v] = x[l]·Ptb[v] + c[b,l]*t[b,v] + Lb[v]  (MFMA)
// ---------------------------------------------------------------------------
__global__ __launch_bounds__(256) void kLogitsBf(const short* __restrict__ xbf,
                                                 const short* __restrict__ Ptb,
                                                 const float* __restrict__ c,
                                                 const float* __restrict__ t,
                                                 const float* __restrict__ Lb,
                                                 float* __restrict__ logits) {
  const int b = blockIdx.z;
  const int i0 = blockIdx.x * 128;  // l
  const int j0 = blockIdx.y * 128;  // v
  const short* Abase = xbf + (size_t)b * L_ * D_;
  const short* Bbase = Ptb + (size_t)b * VP * D_;
  __shared__ short As[128 * 64];
  __shared__ short Bs[128 * 64];
  f32x4 acc[4][4] = {};
  const int tid = threadIdx.x;
  const int w = tid >> 6, lane = tid & 63;
  const int quad = lane >> 4, mcol = lane & 15;
  const int wr0 = (w & 1) * 64, wc0 = (w >> 1) * 64;

  for (int k0 = 0; k0 < D_; k0 += 64) {
#pragma unroll
    for (int q = 0; q < 4; ++q) {
      const int u = q * 256 + tid;
      const int row = u >> 3, blk = u & 7;
      const int phys = blk ^ (row & 7);
      *(short8*)(As + row * 64 + phys * 8) =
          *(const short8*)(Abase + (size_t)(i0 + row) * D_ + k0 + blk * 8);
      *(short8*)(Bs + row * 64 + phys * 8) =
          *(const short8*)(Bbase + (size_t)(j0 + row) * D_ + k0 + blk * 8);
    }
    __syncthreads();
#pragma unroll
    for (int s = 0; s < 2; ++s) {
      short8 af[4], bf[4];
#pragma unroll
      for (int i = 0; i < 4; ++i) {
        const int arow = wr0 + i * 16 + mcol;
        const int ablk = (s * 4 + quad) ^ (arow & 7);
        af[i] = *(const short8*)(As + arow * 64 + ablk * 8);
        const int brow = wc0 + i * 16 + mcol;
        const int bblk = (s * 4 + quad) ^ (brow & 7);
        bf[i] = *(const short8*)(Bs + brow * 64 + bblk * 8);
      }
#pragma unroll
      for (int i = 0; i < 4; ++i)
#pragma unroll
        for (int j = 0; j < 4; ++j)
          acc[i][j] = __builtin_amdgcn_mfma_f32_16x16x32_bf16(af[i], bf[j],
                                                              acc[i][j], 0, 0, 0);
    }
    __syncthreads();
  }
#pragma unroll
  for (int i = 0; i < 4; ++i)
#pragma unroll
    for (int j = 0; j < 4; ++j) {
      const int gv = j0 + wc0 + j * 16 + mcol;
      const float tv = t[b * VP + gv];
      const float lbv = (gv < V_) ? Lb[gv] : 0.f;
#pragma unroll
      for (int r = 0; r < 4; ++r) {
        const int gl = i0 + wr0 + i * 16 + quad * 4 + r;
        logits[((size_t)b * L_ + gl) * VP + gv] =
            acc[i][j][r] + c[b * L_ + gl] * tv + lbv;
      }
    }
}

// ---------------------------------------------------------------------------
// kLsm: log_softmax over V per (b,l) row; write out (L, B, V)
// ---------------------------------------------------------------------------
__global__ __launch_bounds__(256) void kLsm(const float* __restrict__ logits,
                                            float* __restrict__ out) {
  const int l = blockIdx.x, b = blockIdx.y;
  const int tid = threadIdx.x;
  const int lane = tid & 63, w = tid >> 6;
  const float* row = logits + ((size_t)b * L_ + l) * VP;
  float vals[4];
  float vmax = -__builtin_inff();
#pragma unroll
  for (int j = 0; j < 4; ++j) {
    const int v = tid + j * 256;
    vals[j] = (v < V_) ? row[v] : -__builtin_inff();
    vmax = fmaxf(vmax, vals[j]);
  }
  for (int off = 32; off; off >>= 1) vmax = fmaxf(vmax, __shfl_down(vmax, off));
  __shared__ float red_max[4];
  __shared__ float red_sum[4];
  if (lane == 0) red_max[w] = vmax;
  __syncthreads();
  const float m = fmaxf(fmaxf(red_max[0], red_max[1]),
                        fmaxf(red_max[2], red_max[3]));
  float se = 0.f;
#pragma unroll
  for (int j = 0; j < 4; ++j) se += expf(vals[j] - m);
  for (int off = 32; off; off >>= 1) se += __shfl_down(se, off);
  if (lane == 0) red_sum[w] = se;
  __syncthreads();
  const float lse = m + logf(red_sum[0] + red_sum[1] + red_sum[2] + red_sum[3]);
  float* orow = out + (size_t)l * (B_ * V_) + b * V_;
#pragma unroll
  for (int j = 0; j < 4; ++j) {
    const int v = tid + j * 256;
    if (v < V_) orow[v] = vals[j] - lse;
  }
}

// ---------------------------------------------------------------------------
extern "C" void kernel_launch(void* const* d_in, const int* in_sizes, int n_in,
                              void* d_out, int out_size, void* d_ws,
                              size_t ws_size, hipStream_t stream) {
  const float* x  = (const float*)d_in[0];
  const float* Ww = (const float*)d_in[1];
  const float* Wb = (const float*)d_in[2];
  const float* Lw = (const float*)d_in[3];
  const float* Lb = (const float*)d_in[4];

  char* wp = (char*)d_ws;
  short* xbf = (short*)wp;  wp += (size_t)B_ * L_ * D_ * 2;       // 16 MB
  short* xT  = (short*)wp;  wp += (size_t)B_ * L_ * D_ * 2;       // 16 MB
  short* Ptb = (short*)wp;  wp += (size_t)B_ * VP * D_ * 2;       // 4 MB
  float* Gpart = (float*)wp; wp += (size_t)B_ * NCH * D_ * D_ * 4; // 32 MB
  float* G   = (float*)wp;  wp += (size_t)B_ * D_ * D_ * 4;       // 4 MB
  float* M   = (float*)wp;  wp += (size_t)B_ * D_ * D_ * 4;       // 4 MB
  float* s   = (float*)wp;  wp += (size_t)B_ * D_ * 4;
  float* c   = (float*)wp;  wp += (size_t)B_ * L_ * 4;
  float* t   = (float*)wp;  wp += (size_t)B_ * VP * 4;
  float* logits = (float*)wp;                                     // 64 MB

  hipMemsetAsync(s, 0, (size_t)B_ * D_ * sizeof(float), stream);

  kCastX<<<dim3(64, 8, B_), 256, 0, stream>>>(x, xbf, xT);
  kS<<<dim3(64, B_), 256, 0, stream>>>(x, s);
  kC<<<dim3(L_ / 4, B_), 256, 0, stream>>>(x, Wb, c);
  kGbf<<<dim3(4, 4, B_ * NCH), 256, 0, stream>>>(xT, Gpart);
  kGreduce<<<dim3(1024), 256, 0, stream>>>(Gpart, G);
  kM<<<dim3(8, 8, B_), 256, 0, stream>>>(Ww, G, M);
  kT<<<dim3(1024), 256, 0, stream>>>(Lw, s, t);
  kP<<<dim3(16, 8, B_), 256, 0, stream>>>(M, Lw, Ptb);
  kLogitsBf<<<dim3(32, 8, B_), 256, 0, stream>>>(xbf, Ptb, c, t, Lb, logits);
  kLsm<<<dim3(L_, B_), 256, 0, stream>>>(logits, (float*)d_out);
}

// Round 3
// 207.735 us; speedup vs baseline: 3.0796x; 1.3039x over previous
//
#include <hip/hip_runtime.h>
#include <math.h>

#define L_ 4096
#define B_ 4
#define D_ 512
#define V_ 1000
#define VP 1024
#define BD 2048  // B_*D_
#define NCH 8    // split-K chunks for kGbf

typedef __attribute__((ext_vector_type(8))) short short8;
typedef __attribute__((ext_vector_type(4))) float f32x4;
typedef __attribute__((ext_vector_type(4))) short short4v;

__device__ __forceinline__ short f2bf(float f) {
  unsigned u = __float_as_uint(f);
  unsigned r = (u + 0x7FFFu + ((u >> 16) & 1u)) >> 16;
  return (short)r;
}
__device__ __forceinline__ float bf2f(short v) {
  return __uint_as_float(((unsigned)(unsigned short)v) << 16);
}

// ---------------------------------------------------------------------------
// kPre: one pass over x. Produces:
//   xbf (B,L,D) bf16 ; xT (B,D,L) bf16 ; s[b,d]=sum_l x (atomic, bf16-sourced);
//   c[b,l]=dot(x[l,b,:],Wb) (atomic, fp32-sourced)
// ---------------------------------------------------------------------------
__global__ __launch_bounds__(256) void kPre(const float* __restrict__ x,
                                            const float* __restrict__ Wb,
                                            short* __restrict__ xbf,
                                            short* __restrict__ xT,
                                            float* __restrict__ s,
                                            float* __restrict__ c) {
  const int l0 = blockIdx.x * 64, d0 = blockIdx.y * 64, b = blockIdx.z;
  __shared__ short tile[64 * 72];  // tile[d_local][l_local], stride 72
  const int tid = threadIdx.x;
  const int r = tid >> 2;          // row within tile
  const int q = tid & 3;
  const int c0 = q * 16;

  short sv[16];
  float cpart = 0.f;
  const float* src = x + (size_t)(l0 + r) * BD + b * D_ + d0 + c0;
#pragma unroll
  for (int qq = 0; qq < 4; ++qq) {
    float4 f = *(const float4*)(src + qq * 4);
    const float* wb = Wb + d0 + c0 + qq * 4;
    cpart += f.x * wb[0] + f.y * wb[1] + f.z * wb[2] + f.w * wb[3];
    sv[qq * 4 + 0] = f2bf(f.x); sv[qq * 4 + 1] = f2bf(f.y);
    sv[qq * 4 + 2] = f2bf(f.z); sv[qq * 4 + 3] = f2bf(f.w);
  }
  short* dst = xbf + ((size_t)b * L_ + l0 + r) * D_ + d0 + c0;
  *(short8*)(dst)     = *(short8*)(sv);
  *(short8*)(dst + 8) = *(short8*)(sv + 8);
#pragma unroll
  for (int i = 0; i < 16; ++i) tile[(c0 + i) * 72 + r] = sv[i];
  // c partial: reduce across the 4 lanes sharing row r
  cpart += __shfl_xor(cpart, 1);
  cpart += __shfl_xor(cpart, 2);
  if (q == 0) atomicAdd(&c[b * L_ + l0 + r], cpart);
  __syncthreads();
  // phase 2: write xT rows (d-major, l contiguous) + s partials
  short8 t0 = *(const short8*)(tile + r * 72 + c0);
  short8 t1 = *(const short8*)(tile + r * 72 + c0 + 8);
  short* tdst = xT + ((size_t)b * D_ + d0 + r) * L_ + l0 + c0;
  *(short8*)(tdst)     = t0;
  *(short8*)(tdst + 8) = t1;
  float spart = 0.f;
#pragma unroll
  for (int i = 0; i < 8; ++i) spart += bf2f(t0[i]) + bf2f(t1[i]);
  spart += __shfl_xor(spart, 1);
  spart += __shfl_xor(spart, 2);
  if (q == 0) atomicAdd(&s[b * D_ + d0 + r], spart);
}

// ---------------------------------------------------------------------------
// kCastW: Ww -> Wwb (bf16), Lw -> Lwb (bf16, VP rows, zero-pad v>=V_)
// ---------------------------------------------------------------------------
__global__ __launch_bounds__(256) void kCastW(const float* __restrict__ Ww,
                                              const float* __restrict__ Lw,
                                              short* __restrict__ Wwb,
                                              short* __restrict__ Lwb) {
  const int idx = blockIdx.x * 256 + threadIdx.x;  // quad index
  if (idx < 65536) {
    const int e = idx * 4;
    float4 f = *(const float4*)(Ww + e);
    short4v o; o[0] = f2bf(f.x); o[1] = f2bf(f.y); o[2] = f2bf(f.z); o[3] = f2bf(f.w);
    *(short4v*)(Wwb + e) = o;
  } else {
    const int e = (idx - 65536) * 4;
    const int v = e >> 9;
    short4v o = {};
    if (v < V_) {
      float4 f = *(const float4*)(Lw + e);
      o[0] = f2bf(f.x); o[1] = f2bf(f.y); o[2] = f2bf(f.z); o[3] = f2bf(f.w);
    }
    *(short4v*)(Lwb + e) = o;
  }
}

// ---------------------------------------------------------------------------
// kT: t[b][v] = dot(Lw[v,:], s[b,:]); v >= V_ -> 0
// ---------------------------------------------------------------------------
__global__ __launch_bounds__(256) void kT(const float* __restrict__ Lw,
                                          const float* __restrict__ s,
                                          float* __restrict__ t) {
  const int w = threadIdx.x >> 6, lane = threadIdx.x & 63;
  const int wid = blockIdx.x * 4 + w;
  const int b = wid >> 10, v = wid & 1023;
  float sum = 0.f;
  if (v < V_) {
    const float* lr = Lw + (size_t)v * D_;
    const float* sb = s + b * D_;
#pragma unroll
    for (int i = 0; i < 8; ++i) sum += lr[lane + i * 64] * sb[lane + i * 64];
  }
  for (int off = 32; off; off >>= 1) sum += __shfl_down(sum, off);
  if (lane == 0) t[b * VP + v] = (v < V_) ? sum : 0.f;
}

// ---------------------------------------------------------------------------
// kGbf: Gpart[z] = xT_b[:,chunk] . xT_b[:,chunk]^T  (bf16 out, 128x128 tiles)
// ---------------------------------------------------------------------------
__global__ __launch_bounds__(256) void kGbf(const short* __restrict__ xT,
                                            short* __restrict__ Gpart) {
  const int z = blockIdx.z;
  const int b = z >> 3, ch = z & 7;
  const int i0 = blockIdx.x * 128, j0 = blockIdx.y * 128;
  const short* Ab = xT + (size_t)b * D_ * L_;
  __shared__ short As[128 * 64];
  __shared__ short Bs[128 * 64];
  f32x4 acc[4][4] = {};
  const int tid = threadIdx.x;
  const int w = tid >> 6, lane = tid & 63;
  const int quad = lane >> 4, mcol = lane & 15;
  const int wr0 = (w & 1) * 64, wc0 = (w >> 1) * 64;
  const int kbase = ch * 512;

  for (int k0 = kbase; k0 < kbase + 512; k0 += 64) {
#pragma unroll
    for (int q = 0; q < 4; ++q) {
      const int u = q * 256 + tid;
      const int row = u >> 3, blk = u & 7;
      const int phys = blk ^ (row & 7);
      *(short8*)(As + row * 64 + phys * 8) =
          *(const short8*)(Ab + (size_t)(i0 + row) * L_ + k0 + blk * 8);
      *(short8*)(Bs + row * 64 + phys * 8) =
          *(const short8*)(Ab + (size_t)(j0 + row) * L_ + k0 + blk * 8);
    }
    __syncthreads();
#pragma unroll
    for (int ss = 0; ss < 2; ++ss) {
      short8 af[4], bf[4];
#pragma unroll
      for (int i = 0; i < 4; ++i) {
        const int arow = wr0 + i * 16 + mcol;
        const int ablk = (ss * 4 + quad) ^ (arow & 7);
        af[i] = *(const short8*)(As + arow * 64 + ablk * 8);
        const int brow = wc0 + i * 16 + mcol;
        const int bblk = (ss * 4 + quad) ^ (brow & 7);
        bf[i] = *(const short8*)(Bs + brow * 64 + bblk * 8);
      }
#pragma unroll
      for (int i = 0; i < 4; ++i)
#pragma unroll
        for (int j = 0; j < 4; ++j)
          acc[i][j] = __builtin_amdgcn_mfma_f32_16x16x32_bf16(af[i], bf[j],
                                                              acc[i][j], 0, 0, 0);
    }
    __syncthreads();
  }
  short* Gp = Gpart + (size_t)z * (D_ * D_);
#pragma unroll
  for (int i = 0; i < 4; ++i)
#pragma unroll
    for (int j = 0; j < 4; ++j) {
      const int col = j0 + wc0 + j * 16 + mcol;
#pragma unroll
      for (int r = 0; r < 4; ++r) {
        const int rowi = i0 + wr0 + i * 16 + quad * 4 + r;
        Gp[(size_t)rowi * D_ + col] = f2bf(acc[i][j][r]);
      }
    }
}

// ---------------------------------------------------------------------------
// kGreduce: Gb = sum_ch Gpart (bf16 in, bf16 out)
// ---------------------------------------------------------------------------
__global__ __launch_bounds__(256) void kGreduce(const short* __restrict__ Gpart,
                                                short* __restrict__ Gb) {
  const int idx = blockIdx.x * 256 + threadIdx.x;  // short8 index
  const int b = idx >> 15, e = (idx & 32767) * 8;
  float sum[8] = {};
#pragma unroll
  for (int ch = 0; ch < NCH; ++ch) {
    short8 v = *(const short8*)(Gpart + ((size_t)(b * NCH + ch)) * (D_ * D_) + e);
#pragma unroll
    for (int i = 0; i < 8; ++i) sum[i] += bf2f(v[i]);
  }
  short8 o;
#pragma unroll
  for (int i = 0; i < 8; ++i) o[i] = f2bf(sum[i]);
  *(short8*)(Gb + (size_t)b * (D_ * D_) + e) = o;
}

// ---------------------------------------------------------------------------
// kMbf: Mb[b] = Wwb @ Gb[b]  (G symmetric -> B operand = Gb rows), bf16 out
// ---------------------------------------------------------------------------
__global__ __launch_bounds__(256) void kMbf(const short* __restrict__ Wwb,
                                            const short* __restrict__ Gb,
                                            short* __restrict__ Mb) {
  const int b = blockIdx.z;
  const int i0 = blockIdx.x * 128, j0 = blockIdx.y * 128;
  const short* Bbase = Gb + (size_t)b * D_ * D_;
  __shared__ short As[128 * 64];
  __shared__ short Bs[128 * 64];
  f32x4 acc[4][4] = {};
  const int tid = threadIdx.x;
  const int w = tid >> 6, lane = tid & 63;
  const int quad = lane >> 4, mcol = lane & 15;
  const int wr0 = (w & 1) * 64, wc0 = (w >> 1) * 64;

  for (int k0 = 0; k0 < D_; k0 += 64) {
#pragma unroll
    for (int q = 0; q < 4; ++q) {
      const int u = q * 256 + tid;
      const int row = u >> 3, blk = u & 7;
      const int phys = blk ^ (row & 7);
      *(short8*)(As + row * 64 + phys * 8) =
          *(const short8*)(Wwb + (size_t)(i0 + row) * D_ + k0 + blk * 8);
      *(short8*)(Bs + row * 64 + phys * 8) =
          *(const short8*)(Bbase + (size_t)(j0 + row) * D_ + k0 + blk * 8);
    }
    __syncthreads();
#pragma unroll
    for (int ss = 0; ss < 2; ++ss) {
      short8 af[4], bf[4];
#pragma unroll
      for (int i = 0; i < 4; ++i) {
        const int arow = wr0 + i * 16 + mcol;
        const int ablk = (ss * 4 + quad) ^ (arow & 7);
        af[i] = *(const short8*)(As + arow * 64 + ablk * 8);
        const int brow = wc0 + i * 16 + mcol;
        const int bblk = (ss * 4 + quad) ^ (brow & 7);
        bf[i] = *(const short8*)(Bs + brow * 64 + bblk * 8);
      }
#pragma unroll
      for (int i = 0; i < 4; ++i)
#pragma unroll
        for (int j = 0; j < 4; ++j)
          acc[i][j] = __builtin_amdgcn_mfma_f32_16x16x32_bf16(af[i], bf[j],
                                                              acc[i][j], 0, 0, 0);
    }
    __syncthreads();
  }
  short* Mo = Mb + (size_t)b * D_ * D_;
#pragma unroll
  for (int i = 0; i < 4; ++i)
#pragma unroll
    for (int j = 0; j < 4; ++j) {
      const int col = j0 + wc0 + j * 16 + mcol;
#pragma unroll
      for (int r = 0; r < 4; ++r) {
        const int rowi = i0 + wr0 + i * 16 + quad * 4 + r;
        Mo[(size_t)rowi * D_ + col] = f2bf(acc[i][j][r]);
      }
    }
}

// ---------------------------------------------------------------------------
// kPbf: Ptb[b][v][d] = sum_j Lwb[v,j] * Mb[b][d,j]  (bf16 MFMA, bf16 out)
// ---------------------------------------------------------------------------
__global__ __launch_bounds__(256) void kPbf(const short* __restrict__ Lwb,
                                            const short* __restrict__ Mb,
                                            short* __restrict__ Ptb) {
  const int b = blockIdx.z;
  const int i0 = blockIdx.x * 128;  // v
  const int j0 = blockIdx.y * 128;  // d
  const short* Bbase = Mb + (size_t)b * D_ * D_;
  __shared__ short As[128 * 64];
  __shared__ short Bs[128 * 64];
  f32x4 acc[4][4] = {};
  const int tid = threadIdx.x;
  const int w = tid >> 6, lane = tid & 63;
  const int quad = lane >> 4, mcol = lane & 15;
  const int wr0 = (w & 1) * 64, wc0 = (w >> 1) * 64;

  for (int k0 = 0; k0 < D_; k0 += 64) {
#pragma unroll
    for (int q = 0; q < 4; ++q) {
      const int u = q * 256 + tid;
      const int row = u >> 3, blk = u & 7;
      const int phys = blk ^ (row & 7);
      *(short8*)(As + row * 64 + phys * 8) =
          *(const short8*)(Lwb + (size_t)(i0 + row) * D_ + k0 + blk * 8);
      *(short8*)(Bs + row * 64 + phys * 8) =
          *(const short8*)(Bbase + (size_t)(j0 + row) * D_ + k0 + blk * 8);
    }
    __syncthreads();
#pragma unroll
    for (int ss = 0; ss < 2; ++ss) {
      short8 af[4], bf[4];
#pragma unroll
      for (int i = 0; i < 4; ++i) {
        const int arow = wr0 + i * 16 + mcol;
        const int ablk = (ss * 4 + quad) ^ (arow & 7);
        af[i] = *(const short8*)(As + arow * 64 + ablk * 8);
        const int brow = wc0 + i * 16 + mcol;
        const int bblk = (ss * 4 + quad) ^ (brow & 7);
        bf[i] = *(const short8*)(Bs + brow * 64 + bblk * 8);
      }
#pragma unroll
      for (int i = 0; i < 4; ++i)
#pragma unroll
        for (int j = 0; j < 4; ++j)
          acc[i][j] = __builtin_amdgcn_mfma_f32_16x16x32_bf16(af[i], bf[j],
                                                              acc[i][j], 0, 0, 0);
    }
    __syncthreads();
  }
  short* Po = Ptb + (size_t)b * VP * D_;
#pragma unroll
  for (int i = 0; i < 4; ++i)
#pragma unroll
    for (int j = 0; j < 4; ++j) {
      const int col = j0 + wc0 + j * 16 + mcol;
#pragma unroll
      for (int r = 0; r < 4; ++r) {
        const int rowi = i0 + wr0 + i * 16 + quad * 4 + r;
        Po[(size_t)rowi * D_ + col] = f2bf(acc[i][j][r]);
      }
    }
}

// ---------------------------------------------------------------------------
// kLogitsBf: logits[b,l,v] = x[l]·Ptb[v] + c[b,l]*t[b,v] + Lb[v]  (MFMA)
// ---------------------------------------------------------------------------
__global__ __launch_bounds__(256) void kLogitsBf(const short* __restrict__ xbf,
                                                 const short* __restrict__ Ptb,
                                                 const float* __restrict__ c,
                                                 const float* __restrict__ t,
                                                 const float* __restrict__ Lb,
                                                 float* __restrict__ logits) {
  const int b = blockIdx.z;
  const int i0 = blockIdx.x * 128;  // l
  const int j0 = blockIdx.y * 128;  // v
  const short* Abase = xbf + (size_t)b * L_ * D_;
  const short* Bbase = Ptb + (size_t)b * VP * D_;
  __shared__ short As[128 * 64];
  __shared__ short Bs[128 * 64];
  f32x4 acc[4][4] = {};
  const int tid = threadIdx.x;
  const int w = tid >> 6, lane = tid & 63;
  const int quad = lane >> 4, mcol = lane & 15;
  const int wr0 = (w & 1) * 64, wc0 = (w >> 1) * 64;

  for (int k0 = 0; k0 < D_; k0 += 64) {
#pragma unroll
    for (int q = 0; q < 4; ++q) {
      const int u = q * 256 + tid;
      const int row = u >> 3, blk = u & 7;
      const int phys = blk ^ (row & 7);
      *(short8*)(As + row * 64 + phys * 8) =
          *(const short8*)(Abase + (size_t)(i0 + row) * D_ + k0 + blk * 8);
      *(short8*)(Bs + row * 64 + phys * 8) =
          *(const short8*)(Bbase + (size_t)(j0 + row) * D_ + k0 + blk * 8);
    }
    __syncthreads();
#pragma unroll
    for (int ss = 0; ss < 2; ++ss) {
      short8 af[4], bf[4];
#pragma unroll
      for (int i = 0; i < 4; ++i) {
        const int arow = wr0 + i * 16 + mcol;
        const int ablk = (ss * 4 + quad) ^ (arow & 7);
        af[i] = *(const short8*)(As + arow * 64 + ablk * 8);
        const int brow = wc0 + i * 16 + mcol;
        const int bblk = (ss * 4 + quad) ^ (brow & 7);
        bf[i] = *(const short8*)(Bs + brow * 64 + bblk * 8);
      }
#pragma unroll
      for (int i = 0; i < 4; ++i)
#pragma unroll
        for (int j = 0; j < 4; ++j)
          acc[i][j] = __builtin_amdgcn_mfma_f32_16x16x32_bf16(af[i], bf[j],
                                                              acc[i][j], 0, 0, 0);
    }
    __syncthreads();
  }
#pragma unroll
  for (int i = 0; i < 4; ++i)
#pragma unroll
    for (int j = 0; j < 4; ++j) {
      const int gv = j0 + wc0 + j * 16 + mcol;
      const float tv = t[b * VP + gv];
      const float lbv = (gv < V_) ? Lb[gv] : 0.f;
#pragma unroll
      for (int r = 0; r < 4; ++r) {
        const int gl = i0 + wr0 + i * 16 + quad * 4 + r;
        logits[((size_t)b * L_ + gl) * VP + gv] =
            acc[i][j][r] + c[b * L_ + gl] * tv + lbv;
      }
    }
}

// ---------------------------------------------------------------------------
// kLsm: log_softmax over V per (b,l) row; write out (L, B, V)
// ---------------------------------------------------------------------------
__global__ __launch_bounds__(256) void kLsm(const float* __restrict__ logits,
                                            float* __restrict__ out) {
  const int l = blockIdx.x, b = blockIdx.y;
  const int tid = threadIdx.x;
  const int lane = tid & 63, w = tid >> 6;
  const float* row = logits + ((size_t)b * L_ + l) * VP;
  float vals[4];
  float vmax = -__builtin_inff();
#pragma unroll
  for (int j = 0; j < 4; ++j) {
    const int v = tid + j * 256;
    vals[j] = (v < V_) ? row[v] : -__builtin_inff();
    vmax = fmaxf(vmax, vals[j]);
  }
  for (int off = 32; off; off >>= 1) vmax = fmaxf(vmax, __shfl_down(vmax, off));
  __shared__ float red_max[4];
  __shared__ float red_sum[4];
  if (lane == 0) red_max[w] = vmax;
  __syncthreads();
  const float m = fmaxf(fmaxf(red_max[0], red_max[1]),
                        fmaxf(red_max[2], red_max[3]));
  float se = 0.f;
#pragma unroll
  for (int j = 0; j < 4; ++j) se += expf(vals[j] - m);
  for (int off = 32; off; off >>= 1) se += __shfl_down(se, off);
  if (lane == 0) red_sum[w] = se;
  __syncthreads();
  const float lse = m + logf(red_sum[0] + red_sum[1] + red_sum[2] + red_sum[3]);
  float* orow = out + (size_t)l * (B_ * V_) + b * V_;
#pragma unroll
  for (int j = 0; j < 4; ++j) {
    const int v = tid + j * 256;
    if (v < V_) orow[v] = vals[j] - lse;
  }
}

// ---------------------------------------------------------------------------
extern "C" void kernel_launch(void* const* d_in, const int* in_sizes, int n_in,
                              void* d_out, int out_size, void* d_ws,
                              size_t ws_size, hipStream_t stream) {
  const float* x  = (const float*)d_in[0];
  const float* Ww = (const float*)d_in[1];
  const float* Wb = (const float*)d_in[2];
  const float* Lw = (const float*)d_in[3];
  const float* Lb = (const float*)d_in[4];

  char* wp = (char*)d_ws;
  short* xbf = (short*)wp;   wp += (size_t)B_ * L_ * D_ * 2;        // 16 MB
  short* xT  = (short*)wp;   wp += (size_t)B_ * L_ * D_ * 2;        // 16 MB
  short* Ptb = (short*)wp;   wp += (size_t)B_ * VP * D_ * 2;        // 4 MB
  short* Gpart = (short*)wp; wp += (size_t)B_ * NCH * D_ * D_ * 2;  // 16 MB
  short* Gb  = (short*)wp;   wp += (size_t)B_ * D_ * D_ * 2;        // 2 MB
  short* Mb  = (short*)wp;   wp += (size_t)B_ * D_ * D_ * 2;        // 2 MB
  short* Wwb = (short*)wp;   wp += (size_t)D_ * D_ * 2;             // 0.5 MB
  short* Lwb = (short*)wp;   wp += (size_t)VP * D_ * 2;             // 1 MB
  float* s   = (float*)wp;   wp += (size_t)B_ * D_ * 4;             // 8 KB
  float* c   = (float*)wp;   wp += (size_t)B_ * L_ * 4;             // 64 KB
  float* t   = (float*)wp;   wp += (size_t)B_ * VP * 4;             // 16 KB
  float* logits = (float*)wp;                                       // 64 MB

  // zero the atomic accumulators (s and c are contiguous)
  hipMemsetAsync(s, 0, (size_t)(B_ * D_ + B_ * L_) * sizeof(float), stream);

  kCastW<<<dim3(768), 256, 0, stream>>>(Ww, Lw, Wwb, Lwb);
  kPre<<<dim3(64, 8, B_), 256, 0, stream>>>(x, Wb, xbf, xT, s, c);
  kGbf<<<dim3(4, 4, B_ * NCH), 256, 0, stream>>>(xT, Gpart);
  kGreduce<<<dim3(512), 256, 0, stream>>>(Gpart, Gb);
  kMbf<<<dim3(4, 4, B_), 256, 0, stream>>>(Wwb, Gb, Mb);
  kT<<<dim3(1024), 256, 0, stream>>>(Lw, s, t);
  kPbf<<<dim3(8, 4, B_), 256, 0, stream>>>(Lwb, Mb, Ptb);
  kLogitsBf<<<dim3(32, 8, B_), 256, 0, stream>>>(xbf, Ptb, c, t, Lb, logits);
  kLsm<<<dim3(L_, B_), 256, 0, stream>>>(logits, (float*)d_out);
}